// Round 11
// baseline (91.275 us; speedup 1.0000x reference)
//
#include <hip/hip_runtime.h>
#include <math.h>
#include <stdint.h>

#define HW (512*512)
#define TSX 128
#define TSY 32
#define NROW 38              // TSY + 6 halo rows
#define NQ 34                // staged quads/row = (TSX+8)/4
#define LSTRH 68             // dwords per LDS row (=2*NQ, exact; 68%32=4 row stagger)
#define CHS (NROW*LSTRH)

typedef __fp16 h2 __attribute__((ext_vector_type(2)));   // matches cvt_pkrtz / fdot2 types

__device__ __forceinline__ h2 u2h(uint32_t u) { union { uint32_t u; h2 h; } c; c.u = u; return c.h; }
__device__ __forceinline__ uint32_t h2u(h2 h) { union { h2 h; uint32_t u; } c; c.h = h; return c.u; }

#if __has_builtin(__builtin_amdgcn_fdot2)
#define FDOT2(a, b, c) __builtin_amdgcn_fdot2((a), (b), (c), false)
#else
__device__ __forceinline__ float fdot2_asm(h2 a, h2 b, float c) {
    float d;
    asm("v_dot2_f32_f16 %0, %1, %2, %3" : "=v"(d) : "v"(a), "v"(b), "v"(c));
    return d;
}
#define FDOT2(a, b, c) fdot2_asm((a), (b), (c))
#endif

// ---------------- Kernel 1: per-plane partial sums (global avg pool) ----------------
__global__ __launch_bounds__(256) void k_reduce(const float* __restrict__ x,
                                                float* __restrict__ ws) {
    int bid = blockIdx.x;            // 1024 blocks = 128 planes * 8 chunks
    int plane = bid >> 3, j = bid & 7;
    const float4* xv = (const float4*)x + (size_t)plane * 65536 + (size_t)j * 8192;
    int tid = threadIdx.x;
    float s = 0.f;
    #pragma unroll
    for (int k = 0; k < 32; ++k) {
        float4 v = xv[(size_t)k * 256 + tid];
        s += (v.x + v.y) + (v.z + v.w);
    }
    #pragma unroll
    for (int off = 32; off > 0; off >>= 1) s += __shfl_down(s, off, 64);
    __shared__ float red[4];
    if ((tid & 63) == 0) red[tid >> 6] = s;
    __syncthreads();
    if (tid == 0) ws[bid] = (red[0] + red[1]) + (red[2] + red[3]);
}

// ---------------- Kernel 2: finish pool + channel-attention MLP ----------------
__global__ __launch_bounds__(128) void k_mlp(const float* __restrict__ part,
                                             const float* __restrict__ w1,
                                             const float* __restrict__ b1,
                                             const float* __restrict__ w2,
                                             const float* __restrict__ b2,
                                             float* __restrict__ att_out) {
    __shared__ float pool[128];   // [b][c], b=32, c=4
    __shared__ float hbuf[64];    // [b][r], r=2
    int tid = threadIdx.x;
    float s = 0.f;
    #pragma unroll
    for (int j = 0; j < 8; ++j) s += part[tid * 8 + j];
    pool[tid] = s * (1.f / 262144.f);
    __syncthreads();
    if (tid < 64) {
        int b = tid >> 1, r = tid & 1;
        float h = b1[r];
        #pragma unroll
        for (int c = 0; c < 4; ++c) h += w1[r * 4 + c] * pool[b * 4 + c];
        hbuf[tid] = fmaxf(h, 0.f);          // hbuf[b*2+r]
    }
    __syncthreads();
    {
        int b = tid >> 2, c = tid & 3;
        float z = b2[c];
        #pragma unroll
        for (int r = 0; r < 2; ++r) z += w2[c * 2 + r] * hbuf[b * 2 + r];
        att_out[tid] = 1.f / (1.f + __expf(-z));   // att[b*4+c]
    }
}

// ---------------- Kernel 3: fused gate + 1x1 conv + 7x7 conv + sigmoid gate ----------------
// Tile 128x32, 256 threads, thread owns 8 cols x 2 rows (txi=tid&15, tyr=tid>>4).
// LDS col origin = tx0-4, so each (ch,k) window is dwords 4*txi..4*txi+7 ->
// exactly 2 aligned b128 reads (was 3). LDS 31 KB -> 5 blocks/CU (20 waves).
// Weight half2 packs hoisted per-channel (28 cvt, SGPR-uniform source).
// Conv via v_dot2_f32_f16, f32 accumulate.
__global__ __launch_bounds__(256, 5) void k_fused(const float* __restrict__ x,
                                                  const float* __restrict__ conv_w,
                                                  const float* __restrict__ conv_b,
                                                  const float* __restrict__ sa_w,
                                                  const float* __restrict__ sa_b,
                                                  const float* __restrict__ att,
                                                  float* __restrict__ out) {
    __shared__ uint32_t s_pre[3 * CHS];   // 31,008 B
    int tid = threadIdx.x;
    int b = blockIdx.z;
    int ty0 = blockIdx.y * TSY, tx0 = blockIdx.x * TSX;

    // uniform params
    float kw[12], kb[3];
    #pragma unroll
    for (int t = 0; t < 12; ++t) kw[t] = conv_w[t] * att[b * 4 + (t & 3)];
    #pragma unroll
    for (int o = 0; o < 3; ++o) kb[o] = conv_b[o];
    float sbias = sa_b[0];
    const float* xb = x + (size_t)b * 4 * HW;

    // ---- Stage: gated 1x1 conv for tile+halo, packed fp16 into LDS ----
    // row r (0..37): gy = ty0-3+r; quad q (0..33): gx0 = tx0-4+4q (aligned, all-in or all-out)
    for (int u = tid; u < NROW * NQ; u += 256) {
        int r = u / NQ, q = u - r * NQ;
        int gy = ty0 - 3 + r;
        int gx0 = tx0 - 4 + q * 4;
        float4 o0 = make_float4(0.f, 0.f, 0.f, 0.f), o1 = o0, o2 = o0;
        if ((unsigned)gy < 512u && (unsigned)gx0 <= 508u) {
            size_t off = (size_t)gy * 512 + gx0;
            float4 X0 = *(const float4*)(xb + off);
            float4 X1 = *(const float4*)(xb + HW + off);
            float4 X2 = *(const float4*)(xb + 2 * HW + off);
            float4 X3 = *(const float4*)(xb + 3 * HW + off);
#define DO1(comp) \
            o0.comp = kb[0] + kw[0]*X0.comp + kw[1]*X1.comp + kw[2]*X2.comp + kw[3]*X3.comp; \
            o1.comp = kb[1] + kw[4]*X0.comp + kw[5]*X1.comp + kw[6]*X2.comp + kw[7]*X3.comp; \
            o2.comp = kb[2] + kw[8]*X0.comp + kw[9]*X1.comp + kw[10]*X2.comp + kw[11]*X3.comp;
            DO1(x) DO1(y) DO1(z) DO1(w)
#undef DO1
        }
        int base = r * LSTRH + 2 * q;
        *(uint2*)(&s_pre[base]) = make_uint2(h2u(__builtin_amdgcn_cvt_pkrtz(o0.x, o0.y)),
                                             h2u(__builtin_amdgcn_cvt_pkrtz(o0.z, o0.w)));
        *(uint2*)(&s_pre[base + CHS]) = make_uint2(h2u(__builtin_amdgcn_cvt_pkrtz(o1.x, o1.y)),
                                                   h2u(__builtin_amdgcn_cvt_pkrtz(o1.z, o1.w)));
        *(uint2*)(&s_pre[base + 2 * CHS]) = make_uint2(h2u(__builtin_amdgcn_cvt_pkrtz(o2.x, o2.y)),
                                                       h2u(__builtin_amdgcn_cvt_pkrtz(o2.z, o2.w)));
    }
    __syncthreads();

    // ---- 7x7 conv: thread computes 8 cols x 2 rows via dot2 ----
    int txi = tid & 15, tyr = tid >> 4;   // out rows 2*tyr, 2*tyr+1; cols tx0+8*txi..+7
    float acc[2][8];
    #pragma unroll
    for (int i = 0; i < 2; ++i)
        #pragma unroll
        for (int j = 0; j < 8; ++j) acc[i][j] = 0.f;

    #pragma clang loop unroll(disable)
    for (int ch = 0; ch < 3; ++ch) {
        const uint32_t* sbp = &s_pre[ch * CHS];
        // hoisted per-channel packed weights: pw[dy][p] = (w[2p], w[2p+1]), p=3 -> (w6, 0)
        uint32_t pw[7][4];
        #pragma unroll
        for (int dy = 0; dy < 7; ++dy) {
            const float* wr = sa_w + ch * 49 + dy * 7;   // uniform s_loads
            pw[dy][0] = h2u(__builtin_amdgcn_cvt_pkrtz(wr[0], wr[1]));
            pw[dy][1] = h2u(__builtin_amdgcn_cvt_pkrtz(wr[2], wr[3]));
            pw[dy][2] = h2u(__builtin_amdgcn_cvt_pkrtz(wr[4], wr[5]));
            pw[dy][3] = h2u(__builtin_amdgcn_cvt_pkrtz(wr[6], 0.f));
        }
        #pragma unroll
        for (int k = 0; k < 8; ++k) {
            int lr = 2 * tyr + k;                      // logical row 0..37
            const uint32_t* rowp = sbp + lr * LSTRH + 4 * txi;
            uint4 ra = *(const uint4*)(rowp);
            uint4 rb = *(const uint4*)(rowp + 4);
            uint32_t r_[8] = {ra.x, ra.y, ra.z, ra.w, rb.x, rb.y, rb.z, rb.w};
            // half2 pairs pr[h] = (px h, px h+1) relative to px 8*txi; need h=1..14
            uint32_t pr[15];
            #pragma unroll
            for (int m = 0; m < 8; ++m) pr[2 * m < 15 ? 2 * m : 0] = r_[m];   // even h (pr[0] unused by j-loop start h>=1; h=14 from m=7)
            #pragma unroll
            for (int m = 0; m < 7; ++m)
                pr[2 * m + 1] = __builtin_amdgcn_alignbit(r_[m + 1], r_[m], 16);
            #pragma unroll
            for (int i = 0; i < 2; ++i) {
                int dy = k - i;
                if (dy >= 0 && dy <= 6) {
                    h2 w01 = u2h(pw[dy][0]);
                    h2 w23 = u2h(pw[dy][1]);
                    h2 w45 = u2h(pw[dy][2]);
                    h2 w6z = u2h(pw[dy][3]);
                    #pragma unroll
                    for (int j = 0; j < 8; ++j) {
                        float a = acc[i][j];
                        a = FDOT2(w01, u2h(pr[j + 1]), a);
                        a = FDOT2(w23, u2h(pr[j + 3]), a);
                        a = FDOT2(w45, u2h(pr[j + 5]), a);
                        a = FDOT2(w6z, u2h(pr[j + 7]), a);
                        acc[i][j] = a;
                    }
                }
            }
        }
    }

    // ---- Epilogue: sigmoid gate, centers from LDS (2x b64 per ch-row), f32 stores ----
    float* ob = out + (size_t)b * 3 * HW;
    #pragma unroll
    for (int i = 0; i < 2; ++i) {
        float g[8];
        #pragma unroll
        for (int j = 0; j < 8; ++j) g[j] = 1.f / (1.f + __expf(-(acc[i][j] + sbias)));
        int lr = 2 * tyr + 3 + i;                      // center row
        size_t off = (size_t)(ty0 + 2 * tyr + i) * 512 + (tx0 + 8 * txi);
        #pragma unroll
        for (int ch = 0; ch < 3; ++ch) {
            const uint32_t* cp = &s_pre[ch * CHS + lr * LSTRH + 4 * txi + 2];
            uint2 ca = *(const uint2*)(cp);            // px 8txi+4..7
            uint2 cb = *(const uint2*)(cp + 2);        // px 8txi+8..11
            h2 c0 = u2h(ca.x), c1 = u2h(ca.y), c2 = u2h(cb.x), c3 = u2h(cb.y);
            float4 A, B;
            A.x = (float)c0.x * g[0]; A.y = (float)c0.y * g[1];
            A.z = (float)c1.x * g[2]; A.w = (float)c1.y * g[3];
            B.x = (float)c2.x * g[4]; B.y = (float)c2.y * g[5];
            B.z = (float)c3.x * g[6]; B.w = (float)c3.y * g[7];
            *(float4*)(ob + (size_t)ch * HW + off)     = A;
            *(float4*)(ob + (size_t)ch * HW + off + 4) = B;
        }
    }
}

extern "C" void kernel_launch(void* const* d_in, const int* in_sizes, int n_in,
                              void* d_out, int out_size, void* d_ws, size_t ws_size,
                              hipStream_t stream) {
    const float* x      = (const float*)d_in[0];
    const float* ca_w1  = (const float*)d_in[1];
    const float* ca_b1  = (const float*)d_in[2];
    const float* ca_w2  = (const float*)d_in[3];
    const float* ca_b2  = (const float*)d_in[4];
    const float* conv_w = (const float*)d_in[5];
    const float* conv_b = (const float*)d_in[6];
    const float* sa_w   = (const float*)d_in[7];
    const float* sa_b   = (const float*)d_in[8];
    float* ws  = (float*)d_ws;
    float* out = (float*)d_out;

    hipLaunchKernelGGL(k_reduce, dim3(1024), dim3(256), 0, stream, x, ws);
    hipLaunchKernelGGL(k_mlp, dim3(1), dim3(128), 0, stream,
                       ws, ca_w1, ca_b1, ca_w2, ca_b2, ws + 1024);
    hipLaunchKernelGGL(k_fused, dim3(512 / TSX, 512 / TSY, 32), dim3(256), 0, stream,
                       x, conv_w, conv_b, sa_w, sa_b, ws + 1024, out);
}

// Round 12
// 81.769 us; speedup vs baseline: 1.1162x; 1.1162x over previous
//
#include <hip/hip_runtime.h>
#include <math.h>
#include <stdint.h>

#define HW (512*512)
#define TSX 128
#define TSY 32
#define NROW 38              // TSY + 6 halo rows
#define NQ 34                // staged quads/row = (TSX+8)/4
#define LSTRH 68             // dwords per LDS row (=2*NQ; 68%32=4 row stagger)
#define CHS (NROW*LSTRH)
#define NITEMS (NROW*NQ)     // 1292 staging items

typedef __fp16 h2 __attribute__((ext_vector_type(2)));

__device__ __forceinline__ h2 u2h(uint32_t u) { union { uint32_t u; h2 h; } c; c.u = u; return c.h; }
__device__ __forceinline__ uint32_t h2u(h2 h) { union { h2 h; uint32_t u; } c; c.h = h; return c.u; }

#if __has_builtin(__builtin_amdgcn_fdot2)
#define FDOT2(a, b, c) __builtin_amdgcn_fdot2((a), (b), (c), false)
#else
__device__ __forceinline__ float fdot2_asm(h2 a, h2 b, float c) {
    float d;
    asm("v_dot2_f32_f16 %0, %1, %2, %3" : "=v"(d) : "v"(a), "v"(b), "v"(c));
    return d;
}
#define FDOT2(a, b, c) fdot2_asm((a), (b), (c))
#endif

// ---------------- Kernel 1: per-plane partial sums (global avg pool) ----------------
__global__ __launch_bounds__(256) void k_reduce(const float* __restrict__ x,
                                                float* __restrict__ ws) {
    int bid = blockIdx.x;            // 1024 blocks = 128 planes * 8 chunks
    int plane = bid >> 3, j = bid & 7;
    const float4* xv = (const float4*)x + (size_t)plane * 65536 + (size_t)j * 8192;
    int tid = threadIdx.x;
    float s = 0.f;
    #pragma unroll
    for (int k = 0; k < 32; ++k) {
        float4 v = xv[(size_t)k * 256 + tid];
        s += (v.x + v.y) + (v.z + v.w);
    }
    #pragma unroll
    for (int off = 32; off > 0; off >>= 1) s += __shfl_down(s, off, 64);
    __shared__ float red[4];
    if ((tid & 63) == 0) red[tid >> 6] = s;
    __syncthreads();
    if (tid == 0) ws[bid] = (red[0] + red[1]) + (red[2] + red[3]);
}

// ---------------- Kernel 2: finish pool + channel-attention MLP ----------------
__global__ __launch_bounds__(128) void k_mlp(const float* __restrict__ part,
                                             const float* __restrict__ w1,
                                             const float* __restrict__ b1,
                                             const float* __restrict__ w2,
                                             const float* __restrict__ b2,
                                             float* __restrict__ att_out) {
    __shared__ float pool[128];   // [b][c], b=32, c=4
    __shared__ float hbuf[64];    // [b][r], r=2
    int tid = threadIdx.x;
    float s = 0.f;
    #pragma unroll
    for (int j = 0; j < 8; ++j) s += part[tid * 8 + j];
    pool[tid] = s * (1.f / 262144.f);
    __syncthreads();
    if (tid < 64) {
        int b = tid >> 1, r = tid & 1;
        float h = b1[r];
        #pragma unroll
        for (int c = 0; c < 4; ++c) h += w1[r * 4 + c] * pool[b * 4 + c];
        hbuf[tid] = fmaxf(h, 0.f);          // hbuf[b*2+r]
    }
    __syncthreads();
    {
        int b = tid >> 2, c = tid & 3;
        float z = b2[c];
        #pragma unroll
        for (int r = 0; r < 2; ++r) z += w2[c * 2 + r] * hbuf[b * 2 + r];
        att_out[tid] = 1.f / (1.f + __expf(-z));   // att[b*4+c]
    }
}

// ---------------- Kernel 3: fused gate + 1x1 conv + 7x7 conv + sigmoid gate ----------------
// R11 structure (tile 128x32, 8x2 px/thread, fp16 LDS, dot2 conv) with:
//  (1) staging as 2 batches of 3 unrolled slots: 12 global b128 loads issued
//      back-to-back, then gate+cvt+ds_write (2 memory round trips vs 5-6);
//  (2) dual-phase weight packs (even/odd output px) on aligned LDS pairs
//      -> zero v_alignbit in the conv inner loop.
__global__ __launch_bounds__(256, 5) void k_fused(const float* __restrict__ x,
                                                  const float* __restrict__ conv_w,
                                                  const float* __restrict__ conv_b,
                                                  const float* __restrict__ sa_w,
                                                  const float* __restrict__ sa_b,
                                                  const float* __restrict__ att,
                                                  float* __restrict__ out) {
    __shared__ uint32_t s_pre[3 * CHS];   // 31,008 B -> 5 blocks/CU
    int tid = threadIdx.x;
    int b = blockIdx.z;
    int ty0 = blockIdx.y * TSY, tx0 = blockIdx.x * TSX;

    // uniform params
    float kw[12], kb[3];
    #pragma unroll
    for (int t = 0; t < 12; ++t) kw[t] = conv_w[t] * att[b * 4 + (t & 3)];
    #pragma unroll
    for (int o = 0; o < 3; ++o) kb[o] = conv_b[o];
    float sbias = sa_b[0];
    const float* xb = x + (size_t)b * 4 * HW;

    // gate + pack + LDS write for one staged slot
#define GATEWRITE(Xs, inb_, r_, q_)                                                   \
    {                                                                                 \
        float4 o0 = make_float4(0.f,0.f,0.f,0.f), o1 = o0, o2 = o0;                   \
        if (inb_) {                                                                   \
            float4 X0 = Xs[0], X1 = Xs[1], X2 = Xs[2], X3 = Xs[3];                    \
            o0.x = kb[0] + kw[0]*X0.x + kw[1]*X1.x + kw[2]*X2.x + kw[3]*X3.x;         \
            o0.y = kb[0] + kw[0]*X0.y + kw[1]*X1.y + kw[2]*X2.y + kw[3]*X3.y;         \
            o0.z = kb[0] + kw[0]*X0.z + kw[1]*X1.z + kw[2]*X2.z + kw[3]*X3.z;         \
            o0.w = kb[0] + kw[0]*X0.w + kw[1]*X1.w + kw[2]*X2.w + kw[3]*X3.w;         \
            o1.x = kb[1] + kw[4]*X0.x + kw[5]*X1.x + kw[6]*X2.x + kw[7]*X3.x;         \
            o1.y = kb[1] + kw[4]*X0.y + kw[5]*X1.y + kw[6]*X2.y + kw[7]*X3.y;         \
            o1.z = kb[1] + kw[4]*X0.z + kw[5]*X1.z + kw[6]*X2.z + kw[7]*X3.z;         \
            o1.w = kb[1] + kw[4]*X0.w + kw[5]*X1.w + kw[6]*X2.w + kw[7]*X3.w;         \
            o2.x = kb[2] + kw[8]*X0.x + kw[9]*X1.x + kw[10]*X2.x + kw[11]*X3.x;       \
            o2.y = kb[2] + kw[8]*X0.y + kw[9]*X1.y + kw[10]*X2.y + kw[11]*X3.y;       \
            o2.z = kb[2] + kw[8]*X0.z + kw[9]*X1.z + kw[10]*X2.z + kw[11]*X3.z;       \
            o2.w = kb[2] + kw[8]*X0.w + kw[9]*X1.w + kw[10]*X2.w + kw[11]*X3.w;       \
        }                                                                             \
        int base_ = (r_) * LSTRH + 2 * (q_);                                          \
        *(uint2*)(&s_pre[base_]) = make_uint2(h2u(__builtin_amdgcn_cvt_pkrtz(o0.x, o0.y)),  \
                                              h2u(__builtin_amdgcn_cvt_pkrtz(o0.z, o0.w))); \
        *(uint2*)(&s_pre[base_ + CHS]) = make_uint2(h2u(__builtin_amdgcn_cvt_pkrtz(o1.x, o1.y)),  \
                                                    h2u(__builtin_amdgcn_cvt_pkrtz(o1.z, o1.w))); \
        *(uint2*)(&s_pre[base_ + 2*CHS]) = make_uint2(h2u(__builtin_amdgcn_cvt_pkrtz(o2.x, o2.y)),  \
                                                      h2u(__builtin_amdgcn_cvt_pkrtz(o2.z, o2.w))); \
    }

    // ---- Stage batch A: slots 0..2 (always valid item indices) ----
    {
        float4 Xa[3][4]; bool va[3]; int ra[3], qa[3];
        #pragma unroll
        for (int t = 0; t < 3; ++t) {
            int u = tid + t * 256;
            int r = u / NQ, q = u - r * NQ;
            int gy = ty0 - 3 + r, gx0 = tx0 - 4 + q * 4;
            bool inb = ((unsigned)gy < 512u) && ((unsigned)gx0 <= 508u);
            ra[t] = r; qa[t] = q; va[t] = inb;
            float4 z = make_float4(0.f,0.f,0.f,0.f);
            Xa[t][0] = z; Xa[t][1] = z; Xa[t][2] = z; Xa[t][3] = z;
            if (inb) {
                size_t off = (size_t)gy * 512 + gx0;
                Xa[t][0] = *(const float4*)(xb + off);
                Xa[t][1] = *(const float4*)(xb + HW + off);
                Xa[t][2] = *(const float4*)(xb + 2 * HW + off);
                Xa[t][3] = *(const float4*)(xb + 3 * HW + off);
            }
        }
        #pragma unroll
        for (int t = 0; t < 3; ++t) GATEWRITE(Xa[t], va[t], ra[t], qa[t])
    }
    // ---- Stage batch B: slots 3..5 (slot 5 partial: tid < 12) ----
    {
        float4 Xa[3][4]; bool va[3]; int ra[3], qa[3]; bool lv[3];
        #pragma unroll
        for (int t = 0; t < 3; ++t) {
            int u = tid + (t + 3) * 256;
            bool lim = (u < NITEMS);
            lv[t] = lim;
            int uc = lim ? u : 0;
            int r = uc / NQ, q = uc - r * NQ;
            int gy = ty0 - 3 + r, gx0 = tx0 - 4 + q * 4;
            bool inb = lim && ((unsigned)gy < 512u) && ((unsigned)gx0 <= 508u);
            ra[t] = r; qa[t] = q; va[t] = inb;
            float4 z = make_float4(0.f,0.f,0.f,0.f);
            Xa[t][0] = z; Xa[t][1] = z; Xa[t][2] = z; Xa[t][3] = z;
            if (inb) {
                size_t off = (size_t)gy * 512 + gx0;
                Xa[t][0] = *(const float4*)(xb + off);
                Xa[t][1] = *(const float4*)(xb + HW + off);
                Xa[t][2] = *(const float4*)(xb + 2 * HW + off);
                Xa[t][3] = *(const float4*)(xb + 3 * HW + off);
            }
        }
        #pragma unroll
        for (int t = 0; t < 3; ++t) if (lv[t]) GATEWRITE(Xa[t], va[t], ra[t], qa[t])
    }
#undef GATEWRITE
    __syncthreads();

    // ---- 7x7 conv: thread owns 8 cols x 2 rows; dual-phase packed weights ----
    int txi = tid & 15, tyr = tid >> 4;   // out rows 2*tyr, 2*tyr+1; cols tx0+8*txi..+7
    float acc[2][8];
    #pragma unroll
    for (int i = 0; i < 2; ++i)
        #pragma unroll
        for (int j = 0; j < 8; ++j) acc[i][j] = 0.f;

    #pragma clang loop unroll(disable)
    for (int ch = 0; ch < 3; ++ch) {
        const uint32_t* sbp = &s_pre[ch * CHS];
        // even-phase packs (out px j even, pairs r_[j/2+p]):   (0,w0)(w1,w2)(w3,w4)(w5,w6)
        // odd-phase packs  (out px j odd,  pairs r_[(j+1)/2+p]): (w0,w1)(w2,w3)(w4,w5)(w6,0)
        uint32_t pwE[7][4], pwO[7][4];
        #pragma unroll
        for (int dy = 0; dy < 7; ++dy) {
            const float* wr = sa_w + ch * 49 + dy * 7;   // uniform loads
            pwE[dy][0] = h2u(__builtin_amdgcn_cvt_pkrtz(0.f,   wr[0]));
            pwE[dy][1] = h2u(__builtin_amdgcn_cvt_pkrtz(wr[1], wr[2]));
            pwE[dy][2] = h2u(__builtin_amdgcn_cvt_pkrtz(wr[3], wr[4]));
            pwE[dy][3] = h2u(__builtin_amdgcn_cvt_pkrtz(wr[5], wr[6]));
            pwO[dy][0] = h2u(__builtin_amdgcn_cvt_pkrtz(wr[0], wr[1]));
            pwO[dy][1] = h2u(__builtin_amdgcn_cvt_pkrtz(wr[2], wr[3]));
            pwO[dy][2] = h2u(__builtin_amdgcn_cvt_pkrtz(wr[4], wr[5]));
            pwO[dy][3] = h2u(__builtin_amdgcn_cvt_pkrtz(wr[6], 0.f));
        }
        #pragma unroll
        for (int k = 0; k < 8; ++k) {
            int lr = 2 * tyr + k;                      // logical row 0..37
            const uint32_t* rowp = sbp + lr * LSTRH + 4 * txi;
            uint4 ra = *(const uint4*)(rowp);
            uint4 rb = *(const uint4*)(rowp + 4);
            uint32_t r_[8] = {ra.x, ra.y, ra.z, ra.w, rb.x, rb.y, rb.z, rb.w};
            #pragma unroll
            for (int i = 0; i < 2; ++i) {
                int dy = k - i;
                if (dy >= 0 && dy <= 6) {
                    #pragma unroll
                    for (int jh = 0; jh < 4; ++jh) {
                        float aE = acc[i][2 * jh], aO = acc[i][2 * jh + 1];
                        #pragma unroll
                        for (int p = 0; p < 4; ++p) {
                            aE = FDOT2(u2h(pwE[dy][p]), u2h(r_[jh + p]), aE);
                            aO = FDOT2(u2h(pwO[dy][p]), u2h(r_[jh + p + 1]), aO);
                        }
                        acc[i][2 * jh] = aE; acc[i][2 * jh + 1] = aO;
                    }
                }
            }
        }
    }

    // ---- Epilogue: sigmoid gate, centers from LDS, f32 stores ----
    float* ob = out + (size_t)b * 3 * HW;
    #pragma unroll
    for (int i = 0; i < 2; ++i) {
        float g[8];
        #pragma unroll
        for (int j = 0; j < 8; ++j) g[j] = 1.f / (1.f + __expf(-(acc[i][j] + sbias)));
        int lr = 2 * tyr + 3 + i;                      // center row
        size_t off = (size_t)(ty0 + 2 * tyr + i) * 512 + (tx0 + 8 * txi);
        #pragma unroll
        for (int ch = 0; ch < 3; ++ch) {
            const uint32_t* cp = &s_pre[ch * CHS + lr * LSTRH + 4 * txi + 2];
            uint2 ca = *(const uint2*)(cp);            // px 8txi+4..7
            uint2 cb = *(const uint2*)(cp + 2);        // px 8txi+8..11
            h2 c0 = u2h(ca.x), c1 = u2h(ca.y), c2 = u2h(cb.x), c3 = u2h(cb.y);
            float4 A, B;
            A.x = (float)c0.x * g[0]; A.y = (float)c0.y * g[1];
            A.z = (float)c1.x * g[2]; A.w = (float)c1.y * g[3];
            B.x = (float)c2.x * g[4]; B.y = (float)c2.y * g[5];
            B.z = (float)c3.x * g[6]; B.w = (float)c3.y * g[7];
            *(float4*)(ob + (size_t)ch * HW + off)     = A;
            *(float4*)(ob + (size_t)ch * HW + off + 4) = B;
        }
    }
}

extern "C" void kernel_launch(void* const* d_in, const int* in_sizes, int n_in,
                              void* d_out, int out_size, void* d_ws, size_t ws_size,
                              hipStream_t stream) {
    const float* x      = (const float*)d_in[0];
    const float* ca_w1  = (const float*)d_in[1];
    const float* ca_b1  = (const float*)d_in[2];
    const float* ca_w2  = (const float*)d_in[3];
    const float* ca_b2  = (const float*)d_in[4];
    const float* conv_w = (const float*)d_in[5];
    const float* conv_b = (const float*)d_in[6];
    const float* sa_w   = (const float*)d_in[7];
    const float* sa_b   = (const float*)d_in[8];
    float* ws  = (float*)d_ws;
    float* out = (float*)d_out;

    hipLaunchKernelGGL(k_reduce, dim3(1024), dim3(256), 0, stream, x, ws);
    hipLaunchKernelGGL(k_mlp, dim3(1), dim3(128), 0, stream,
                       ws, ca_w1, ca_b1, ca_w2, ca_b2, ws + 1024);
    hipLaunchKernelGGL(k_fused, dim3(512 / TSX, 512 / TSY, 32), dim3(256), 0, stream,
                       x, conv_w, conv_b, sa_w, sa_b, ws + 1024, out);
}

// Round 13
// 81.008 us; speedup vs baseline: 1.1267x; 1.0094x over previous
//
#include <hip/hip_runtime.h>
#include <math.h>
#include <stdint.h>

#define HW (512*512)
#define TSX 128
#define TSY 32
#define NROW 38              // TSY + 6 halo rows
#define NQ 34                // staged quads/row = (TSX+8)/4
#define LSTRH 68             // dwords per LDS row (=2*NQ; 68%32=4 row stagger)
#define CHS (NROW*LSTRH)
#define NITEMS (NROW*NQ)     // 1292 staging items

typedef __fp16 h2 __attribute__((ext_vector_type(2)));

__device__ __forceinline__ h2 u2h(uint32_t u) { union { uint32_t u; h2 h; } c; c.u = u; return c.h; }
__device__ __forceinline__ uint32_t h2u(h2 h) { union { h2 h; uint32_t u; } c; c.h = h; return c.u; }

#if __has_builtin(__builtin_amdgcn_fdot2)
#define FDOT2(a, b, c) __builtin_amdgcn_fdot2((a), (b), (c), false)
#else
__device__ __forceinline__ float fdot2_asm(h2 a, h2 b, float c) {
    float d;
    asm("v_dot2_f32_f16 %0, %1, %2, %3" : "=v"(d) : "v"(a), "v"(b), "v"(c));
    return d;
}
#define FDOT2(a, b, c) fdot2_asm((a), (b), (c))
#endif

// ---------------- Kernel 1: per-plane partial sums (global avg pool) ----------------
__global__ __launch_bounds__(256) void k_reduce(const float* __restrict__ x,
                                                float* __restrict__ ws) {
    int bid = blockIdx.x;            // 1024 blocks = 128 planes * 8 chunks
    int plane = bid >> 3, j = bid & 7;
    const float4* xv = (const float4*)x + (size_t)plane * 65536 + (size_t)j * 8192;
    int tid = threadIdx.x;
    float s = 0.f;
    #pragma unroll
    for (int k = 0; k < 32; ++k) {
        float4 v = xv[(size_t)k * 256 + tid];
        s += (v.x + v.y) + (v.z + v.w);
    }
    #pragma unroll
    for (int off = 32; off > 0; off >>= 1) s += __shfl_down(s, off, 64);
    __shared__ float red[4];
    if ((tid & 63) == 0) red[tid >> 6] = s;
    __syncthreads();
    if (tid == 0) ws[bid] = (red[0] + red[1]) + (red[2] + red[3]);
}

// ---------------- Kernel 2: finish pool + MLP + pre-pack 7x7 weights ----------------
// out layout in ws (after the 1024 partials): att[128] floats, then 168 packed
// fp16x2 weight dwords: pk[ch*56 + dy*8 + p], p=0..3 E-phase {(0,w0),(w1,w2),
// (w3,w4),(w5,w6)}, p=4..7 O-phase {(w0,w1),(w2,w3),(w4,w5),(w6,0)}.
__global__ __launch_bounds__(256) void k_mlp(const float* __restrict__ part,
                                             const float* __restrict__ w1,
                                             const float* __restrict__ b1,
                                             const float* __restrict__ w2,
                                             const float* __restrict__ b2,
                                             const float* __restrict__ sa_w,
                                             float* __restrict__ att_out) {
    __shared__ float pool[128];   // [b][c], b=32, c=4
    __shared__ float hbuf[64];    // [b][r], r=2
    int tid = threadIdx.x;

    // weight packing (independent of pooling)
    if (tid < 168) {
        int ch = tid / 56, rest = tid - ch * 56;
        int dy = rest >> 3, p = rest & 7;
        const float* wr = sa_w + ch * 49 + dy * 7;
        float a, c;
        if (p < 4) {                      // E-phase
            a = (p == 0) ? 0.f : wr[2 * p - 1];
            c = wr[2 * p];
        } else {                          // O-phase
            int pp = p - 4;
            a = wr[2 * pp];
            c = (pp == 3) ? 0.f : wr[2 * pp + 1];
        }
        ((uint32_t*)att_out)[128 + tid] = h2u(__builtin_amdgcn_cvt_pkrtz(a, c));
    }

    if (tid < 128) {
        float s = 0.f;
        #pragma unroll
        for (int j = 0; j < 8; ++j) s += part[tid * 8 + j];
        pool[tid] = s * (1.f / 262144.f);
    }
    __syncthreads();
    if (tid < 64) {
        int b = tid >> 1, r = tid & 1;
        float h = b1[r];
        #pragma unroll
        for (int c = 0; c < 4; ++c) h += w1[r * 4 + c] * pool[b * 4 + c];
        hbuf[tid] = fmaxf(h, 0.f);          // hbuf[b*2+r]
    }
    __syncthreads();
    if (tid < 128) {
        int b = tid >> 2, c = tid & 3;
        float z = b2[c];
        #pragma unroll
        for (int r = 0; r < 2; ++r) z += w2[c * 2 + r] * hbuf[b * 2 + r];
        att_out[tid] = 1.f / (1.f + __expf(-z));   // att[b*4+c]
    }
}

// ---------------- Kernel 3: fused gate + 1x1 conv + 7x7 conv + sigmoid gate ----------------
// R12 structure (tile 128x32, 8x2 px/thread, fp16 LDS, dual-phase dot2, batched
// staging). ONE change: weight packs are pre-packed by k_mlp and read via
// UNIFORM loads -> SGPR-resident; v_dot2 takes SGPR src0 directly. No per-k
// cvt_pkrtz rematerialization (R12's VGPR=48 showed packs weren't in VGPRs).
__global__ __launch_bounds__(256, 5) void k_fused(const float* __restrict__ x,
                                                  const float* __restrict__ conv_w,
                                                  const float* __restrict__ conv_b,
                                                  const uint32_t* __restrict__ wpk,
                                                  const float* __restrict__ sa_b,
                                                  const float* __restrict__ att,
                                                  float* __restrict__ out) {
    __shared__ uint32_t s_pre[3 * CHS];   // 31,008 B -> 5 blocks/CU
    int tid = threadIdx.x;
    int b = blockIdx.z;
    int ty0 = blockIdx.y * TSY, tx0 = blockIdx.x * TSX;

    // uniform params
    float kw[12], kb[3];
    #pragma unroll
    for (int t = 0; t < 12; ++t) kw[t] = conv_w[t] * att[b * 4 + (t & 3)];
    #pragma unroll
    for (int o = 0; o < 3; ++o) kb[o] = conv_b[o];
    float sbias = sa_b[0];
    const float* xb = x + (size_t)b * 4 * HW;

#define GATEWRITE(Xs, inb_, r_, q_)                                                   \
    {                                                                                 \
        float4 o0 = make_float4(0.f,0.f,0.f,0.f), o1 = o0, o2 = o0;                   \
        if (inb_) {                                                                   \
            float4 X0 = Xs[0], X1 = Xs[1], X2 = Xs[2], X3 = Xs[3];                    \
            o0.x = kb[0] + kw[0]*X0.x + kw[1]*X1.x + kw[2]*X2.x + kw[3]*X3.x;         \
            o0.y = kb[0] + kw[0]*X0.y + kw[1]*X1.y + kw[2]*X2.y + kw[3]*X3.y;         \
            o0.z = kb[0] + kw[0]*X0.z + kw[1]*X1.z + kw[2]*X2.z + kw[3]*X3.z;         \
            o0.w = kb[0] + kw[0]*X0.w + kw[1]*X1.w + kw[2]*X2.w + kw[3]*X3.w;         \
            o1.x = kb[1] + kw[4]*X0.x + kw[5]*X1.x + kw[6]*X2.x + kw[7]*X3.x;         \
            o1.y = kb[1] + kw[4]*X0.y + kw[5]*X1.y + kw[6]*X2.y + kw[7]*X3.y;         \
            o1.z = kb[1] + kw[4]*X0.z + kw[5]*X1.z + kw[6]*X2.z + kw[7]*X3.z;         \
            o1.w = kb[1] + kw[4]*X0.w + kw[5]*X1.w + kw[6]*X2.w + kw[7]*X3.w;         \
            o2.x = kb[2] + kw[8]*X0.x + kw[9]*X1.x + kw[10]*X2.x + kw[11]*X3.x;       \
            o2.y = kb[2] + kw[8]*X0.y + kw[9]*X1.y + kw[10]*X2.y + kw[11]*X3.y;       \
            o2.z = kb[2] + kw[8]*X0.z + kw[9]*X1.z + kw[10]*X2.z + kw[11]*X3.z;       \
            o2.w = kb[2] + kw[8]*X0.w + kw[9]*X1.w + kw[10]*X2.w + kw[11]*X3.w;       \
        }                                                                             \
        int base_ = (r_) * LSTRH + 2 * (q_);                                          \
        *(uint2*)(&s_pre[base_]) = make_uint2(h2u(__builtin_amdgcn_cvt_pkrtz(o0.x, o0.y)),  \
                                              h2u(__builtin_amdgcn_cvt_pkrtz(o0.z, o0.w))); \
        *(uint2*)(&s_pre[base_ + CHS]) = make_uint2(h2u(__builtin_amdgcn_cvt_pkrtz(o1.x, o1.y)),  \
                                                    h2u(__builtin_amdgcn_cvt_pkrtz(o1.z, o1.w))); \
        *(uint2*)(&s_pre[base_ + 2*CHS]) = make_uint2(h2u(__builtin_amdgcn_cvt_pkrtz(o2.x, o2.y)),  \
                                                      h2u(__builtin_amdgcn_cvt_pkrtz(o2.z, o2.w))); \
    }

    // ---- Stage batch A: slots 0..2 ----
    {
        float4 Xa[3][4]; bool va[3]; int ra[3], qa[3];
        #pragma unroll
        for (int t = 0; t < 3; ++t) {
            int u = tid + t * 256;
            int r = u / NQ, q = u - r * NQ;
            int gy = ty0 - 3 + r, gx0 = tx0 - 4 + q * 4;
            bool inb = ((unsigned)gy < 512u) && ((unsigned)gx0 <= 508u);
            ra[t] = r; qa[t] = q; va[t] = inb;
            float4 z = make_float4(0.f,0.f,0.f,0.f);
            Xa[t][0] = z; Xa[t][1] = z; Xa[t][2] = z; Xa[t][3] = z;
            if (inb) {
                size_t off = (size_t)gy * 512 + gx0;
                Xa[t][0] = *(const float4*)(xb + off);
                Xa[t][1] = *(const float4*)(xb + HW + off);
                Xa[t][2] = *(const float4*)(xb + 2 * HW + off);
                Xa[t][3] = *(const float4*)(xb + 3 * HW + off);
            }
        }
        #pragma unroll
        for (int t = 0; t < 3; ++t) GATEWRITE(Xa[t], va[t], ra[t], qa[t])
    }
    // ---- Stage batch B: slots 3..5 (slot 5 partial) ----
    {
        float4 Xa[3][4]; bool va[3]; int ra[3], qa[3]; bool lv[3];
        #pragma unroll
        for (int t = 0; t < 3; ++t) {
            int u = tid + (t + 3) * 256;
            bool lim = (u < NITEMS);
            lv[t] = lim;
            int uc = lim ? u : 0;
            int r = uc / NQ, q = uc - r * NQ;
            int gy = ty0 - 3 + r, gx0 = tx0 - 4 + q * 4;
            bool inb = lim && ((unsigned)gy < 512u) && ((unsigned)gx0 <= 508u);
            ra[t] = r; qa[t] = q; va[t] = inb;
            float4 z = make_float4(0.f,0.f,0.f,0.f);
            Xa[t][0] = z; Xa[t][1] = z; Xa[t][2] = z; Xa[t][3] = z;
            if (inb) {
                size_t off = (size_t)gy * 512 + gx0;
                Xa[t][0] = *(const float4*)(xb + off);
                Xa[t][1] = *(const float4*)(xb + HW + off);
                Xa[t][2] = *(const float4*)(xb + 2 * HW + off);
                Xa[t][3] = *(const float4*)(xb + 3 * HW + off);
            }
        }
        #pragma unroll
        for (int t = 0; t < 3; ++t) if (lv[t]) GATEWRITE(Xa[t], va[t], ra[t], qa[t])
    }
#undef GATEWRITE
    __syncthreads();

    // ---- 7x7 conv: 8 cols x 2 rows per thread; SGPR weights + dual-phase dot2 ----
    int txi = tid & 15, tyr = tid >> 4;
    float acc[2][8];
    #pragma unroll
    for (int i = 0; i < 2; ++i)
        #pragma unroll
        for (int j = 0; j < 8; ++j) acc[i][j] = 0.f;

    #pragma clang loop unroll(disable)
    for (int ch = 0; ch < 3; ++ch) {
        const uint32_t* sbp = &s_pre[ch * CHS];
        const uint32_t* wp = wpk + ch * 56;      // uniform -> s_load, SGPR-resident
        #pragma unroll
        for (int k = 0; k < 8; ++k) {
            int lr = 2 * tyr + k;
            const uint32_t* rowp = sbp + lr * LSTRH + 4 * txi;
            uint4 ra = *(const uint4*)(rowp);
            uint4 rb = *(const uint4*)(rowp + 4);
            uint32_t r_[8] = {ra.x, ra.y, ra.z, ra.w, rb.x, rb.y, rb.z, rb.w};
            #pragma unroll
            for (int i = 0; i < 2; ++i) {
                int dy = k - i;
                if (dy >= 0 && dy <= 6) {
                    #pragma unroll
                    for (int jh = 0; jh < 4; ++jh) {
                        float aE = acc[i][2 * jh], aO = acc[i][2 * jh + 1];
                        #pragma unroll
                        for (int p = 0; p < 4; ++p) {
                            aE = FDOT2(u2h(wp[dy * 8 + p]),     u2h(r_[jh + p]),     aE);
                            aO = FDOT2(u2h(wp[dy * 8 + 4 + p]), u2h(r_[jh + p + 1]), aO);
                        }
                        acc[i][2 * jh] = aE; acc[i][2 * jh + 1] = aO;
                    }
                }
            }
        }
    }

    // ---- Epilogue: sigmoid gate, centers from LDS, f32 stores ----
    float* ob = out + (size_t)b * 3 * HW;
    #pragma unroll
    for (int i = 0; i < 2; ++i) {
        float g[8];
        #pragma unroll
        for (int j = 0; j < 8; ++j) g[j] = 1.f / (1.f + __expf(-(acc[i][j] + sbias)));
        int lr = 2 * tyr + 3 + i;
        size_t off = (size_t)(ty0 + 2 * tyr + i) * 512 + (tx0 + 8 * txi);
        #pragma unroll
        for (int ch = 0; ch < 3; ++ch) {
            const uint32_t* cp = &s_pre[ch * CHS + lr * LSTRH + 4 * txi + 2];
            uint2 ca = *(const uint2*)(cp);
            uint2 cb = *(const uint2*)(cp + 2);
            h2 c0 = u2h(ca.x), c1 = u2h(ca.y), c2 = u2h(cb.x), c3 = u2h(cb.y);
            float4 A, B;
            A.x = (float)c0.x * g[0]; A.y = (float)c0.y * g[1];
            A.z = (float)c1.x * g[2]; A.w = (float)c1.y * g[3];
            B.x = (float)c2.x * g[4]; B.y = (float)c2.y * g[5];
            B.z = (float)c3.x * g[6]; B.w = (float)c3.y * g[7];
            *(float4*)(ob + (size_t)ch * HW + off)     = A;
            *(float4*)(ob + (size_t)ch * HW + off + 4) = B;
        }
    }
}

extern "C" void kernel_launch(void* const* d_in, const int* in_sizes, int n_in,
                              void* d_out, int out_size, void* d_ws, size_t ws_size,
                              hipStream_t stream) {
    const float* x      = (const float*)d_in[0];
    const float* ca_w1  = (const float*)d_in[1];
    const float* ca_b1  = (const float*)d_in[2];
    const float* ca_w2  = (const float*)d_in[3];
    const float* ca_b2  = (const float*)d_in[4];
    const float* conv_w = (const float*)d_in[5];
    const float* conv_b = (const float*)d_in[6];
    const float* sa_w   = (const float*)d_in[7];
    const float* sa_b   = (const float*)d_in[8];
    float* ws  = (float*)d_ws;
    float* out = (float*)d_out;

    float* att = ws + 1024;                          // att[128] then 168 packed dwords
    const uint32_t* wpk = (const uint32_t*)att + 128;

    hipLaunchKernelGGL(k_reduce, dim3(1024), dim3(256), 0, stream, x, ws);
    hipLaunchKernelGGL(k_mlp, dim3(1), dim3(256), 0, stream,
                       ws, ca_w1, ca_b1, ca_w2, ca_b2, sa_w, att);
    hipLaunchKernelGGL(k_fused, dim3(512 / TSX, 512 / TSY, 32), dim3(256), 0, stream,
                       x, conv_w, conv_b, wpk, sa_b, att, out);
}